// Round 1
// baseline (41376.175 us; speedup 1.0000x reference)
//
#include <hip/hip_runtime.h>
#include <math.h>

#define BATCH 512
#define STATE 32
#define ZD    64
#define RNND  512
#define HDIM  512
#define NSTEP 254
#define FCIN  608   // STATE+ZD+RNND
#define LOG2PI 1.8378770664093453f

__device__ __forceinline__ float sigm(float x){ return 1.0f/(1.0f+__expf(-x)); }

// ---------------------------------------------------------------------------
// kernel A: blocks [0,128): fc1   dh1 = relu([s,z,h1] @ Wfc1^T + bfc1)
//           blocks [128,384): gru0  h0_new = GRU(x_in=[s,a], h0_old)
//           blocks [384,400): head(t-1): mean/lv from dh2, nll +=
// ---------------------------------------------------------------------------
__global__ __launch_bounds__(256) void kernelA(
    int t,
    const float* __restrict__ states, const float* __restrict__ zin,
    const float* __restrict__ Wfc1, const float* __restrict__ bfc1,
    const float* __restrict__ Wih0, const float* __restrict__ Whh0,
    const float* __restrict__ bih0, const float* __restrict__ bhh0,
    const float* __restrict__ Wmean, const float* __restrict__ bmean,
    const float* __restrict__ Wlv,  const float* __restrict__ blv,
    const float* __restrict__ h1_old, const float* __restrict__ h0_old,
    float* __restrict__ h0_new, float* __restrict__ dh1,
    const float* __restrict__ dh2, float* __restrict__ nll)
{
  __shared__ float smem[4*32*33];
  const int blk = blockIdx.x;
  const int tid = threadIdx.x;
  const int tr = tid >> 5, tc = tid & 31;

  if (blk < 128) {
    // ---------------- fc1: BM=32 batch x BN=64 out, micro 4x2 ----------------
    if (t >= NSTEP) return;
    const int bm = blk >> 3;   // 0..15
    const int bn = blk & 7;    // 0..7
    float acc[4][2] = {};
    float* Xs = smem;            // [32][33]
    float* Ws = smem + 32*33;    // [64][33]
    const float* st = states + (size_t)t*BATCH*STATE;
    for (int kt = 0; kt < FCIN/32; ++kt) {
      for (int l = tid; l < 32*32; l += 256) {
        int i = l >> 5, kk = l & 31;
        int b = bm*32 + i, k = kt*32 + kk;
        float v;
        if (k < STATE)          v = st[b*STATE + k];
        else if (k < STATE+ZD)  v = zin[b*ZD + (k-STATE)];
        else                    v = h1_old[(size_t)b*RNND + (k-STATE-ZD)];
        Xs[i*33 + kk] = v;
      }
      for (int l = tid; l < 64*32; l += 256) {
        int n = l >> 5, kk = l & 31;
        Ws[n*33 + kk] = Wfc1[(size_t)(bn*64 + n)*FCIN + kt*32 + kk];
      }
      __syncthreads();
      #pragma unroll
      for (int kk = 0; kk < 32; ++kk) {
        float xv[4];
        #pragma unroll
        for (int q = 0; q < 4; ++q) xv[q] = Xs[(tr + 8*q)*33 + kk];
        float w0 = Ws[tc*33 + kk], w1 = Ws[(tc+32)*33 + kk];
        #pragma unroll
        for (int q = 0; q < 4; ++q) { acc[q][0] += xv[q]*w0; acc[q][1] += xv[q]*w1; }
      }
      __syncthreads();
    }
    #pragma unroll
    for (int q = 0; q < 4; ++q) {
      int b = bm*32 + tr + 8*q;
      int n0 = bn*64 + tc, n1 = n0 + 32;
      dh1[(size_t)b*HDIM + n0] = fmaxf(acc[q][0] + bfc1[n0], 0.f);
      dh1[(size_t)b*HDIM + n1] = fmaxf(acc[q][1] + bfc1[n1], 0.f);
    }
  } else if (blk < 384) {
    // ---------------- gru0: BM=32 batch x BN=32 j, 3 gates -------------------
    if (t >= NSTEP) return;
    const int b2 = blk - 128;
    const int bm = b2 >> 4, bn = b2 & 15;
    float aR[4] = {}, aZ[4] = {}, aIN[4] = {}, aHN[4] = {};
    float* Xs = smem;               // [32][33]
    float* Wr = smem + 1*32*33;
    float* Wz = smem + 2*32*33;
    float* Wn = smem + 3*32*33;
    const float* st  = states + (size_t)t*BATCH*STATE;
    const float* st1 = st + BATCH*STATE;
    // phase 1: gi = x_in @ Wih0^T, K=64
    for (int kt = 0; kt < 2; ++kt) {
      for (int l = tid; l < 32*32; l += 256) {
        int i = l >> 5, kk = l & 31;
        int b = bm*32 + i, k = kt*32 + kk;
        float v;
        if (k < STATE) v = st[b*STATE + k];
        else           v = st1[b*STATE + (k-STATE)] - st[b*STATE + (k-STATE)];
        Xs[i*33 + kk] = v;
        int j = bn*32 + i;
        Wr[i*33 + kk] = Wih0[(size_t)(j      )*64 + k];
        Wz[i*33 + kk] = Wih0[(size_t)(j + 512)*64 + k];
        Wn[i*33 + kk] = Wih0[(size_t)(j +1024)*64 + k];
      }
      __syncthreads();
      #pragma unroll
      for (int kk = 0; kk < 32; ++kk) {
        float xv[4];
        #pragma unroll
        for (int q = 0; q < 4; ++q) xv[q] = Xs[(tr + 8*q)*33 + kk];
        float wr = Wr[tc*33+kk], wz = Wz[tc*33+kk], wn = Wn[tc*33+kk];
        #pragma unroll
        for (int q = 0; q < 4; ++q) { aR[q] += xv[q]*wr; aZ[q] += xv[q]*wz; aIN[q] += xv[q]*wn; }
      }
      __syncthreads();
    }
    // phase 2: gh = h0_old @ Whh0^T, K=512
    for (int kt = 0; kt < 16; ++kt) {
      for (int l = tid; l < 32*32; l += 256) {
        int i = l >> 5, kk = l & 31;
        int k = kt*32 + kk;
        Xs[i*33 + kk] = h0_old[(size_t)(bm*32 + i)*RNND + k];
        int j = bn*32 + i;
        Wr[i*33 + kk] = Whh0[(size_t)(j      )*RNND + k];
        Wz[i*33 + kk] = Whh0[(size_t)(j + 512)*RNND + k];
        Wn[i*33 + kk] = Whh0[(size_t)(j +1024)*RNND + k];
      }
      __syncthreads();
      #pragma unroll
      for (int kk = 0; kk < 32; ++kk) {
        float xv[4];
        #pragma unroll
        for (int q = 0; q < 4; ++q) xv[q] = Xs[(tr + 8*q)*33 + kk];
        float wr = Wr[tc*33+kk], wz = Wz[tc*33+kk], wn = Wn[tc*33+kk];
        #pragma unroll
        for (int q = 0; q < 4; ++q) { aR[q] += xv[q]*wr; aZ[q] += xv[q]*wz; aHN[q] += xv[q]*wn; }
      }
      __syncthreads();
    }
    const int j = bn*32 + tc;
    #pragma unroll
    for (int q = 0; q < 4; ++q) {
      int b = bm*32 + tr + 8*q;
      float r  = sigm(aR[q] + bih0[j]       + bhh0[j]);
      float zg = sigm(aZ[q] + bih0[j + 512] + bhh0[j + 512]);
      float n  = tanhf(aIN[q] + bih0[j +1024] + r*(aHN[q] + bhh0[j +1024]));
      float h  = h0_old[(size_t)b*RNND + j];
      h0_new[(size_t)b*RNND + j] = (1.f - zg)*n + zg*h;
    }
  } else {
    // ---------------- head for step tp = t-1 --------------------------------
    if (t < 1) return;
    const int tp = t - 1;
    const int hb = blk - 384;   // batch tile 0..15
    float am[4] = {}, al[4] = {};
    float* Xs = smem;             // [32][33]
    float* Wm = smem + 32*33;
    float* Wl = smem + 2*32*33;
    for (int kt = 0; kt < 16; ++kt) {
      for (int l = tid; l < 32*32; l += 256) {
        int i = l >> 5, kk = l & 31;
        Xs[i*33+kk] = dh2[(size_t)(hb*32 + i)*HDIM + kt*32 + kk];
        Wm[i*33+kk] = Wmean[(size_t)i*HDIM + kt*32 + kk];
        Wl[i*33+kk] = Wlv  [(size_t)i*HDIM + kt*32 + kk];
      }
      __syncthreads();
      #pragma unroll
      for (int kk = 0; kk < 32; ++kk) {
        float wm = Wm[tc*33+kk], wl = Wl[tc*33+kk];
        #pragma unroll
        for (int q = 0; q < 4; ++q) {
          float x = Xs[(tr + 8*q)*33 + kk];
          am[q] += x*wm; al[q] += x*wl;
        }
      }
      __syncthreads();
    }
    const float* st  = states + (size_t)tp*BATCH*STATE;
    const float* st1 = st + BATCH*STATE;
    const int i = tc;
    #pragma unroll
    for (int q = 0; q < 4; ++q) {
      int b = hb*32 + tr + 8*q;
      float mean = am[q] + bmean[i];
      float lv   = al[q] + blv[i];
      float a = st1[b*STATE + i] - st[b*STATE + i];
      float d = a - mean;
      nll[b*STATE + i] += 0.5f*(d*d*__expf(-lv) + lv + LOG2PI);
    }
  }
}

// ---------------------------------------------------------------------------
// kernel B: blocks [0,128): fc2   dh2 = relu(dh1 @ Wfc2^T + bfc2)
//           blocks [128,384): gru1  h1_new = GRU(h0_new, h1_old)
// ---------------------------------------------------------------------------
__global__ __launch_bounds__(256) void kernelB(
    const float* __restrict__ Wfc2, const float* __restrict__ bfc2,
    const float* __restrict__ Wih1, const float* __restrict__ Whh1,
    const float* __restrict__ bih1, const float* __restrict__ bhh1,
    const float* __restrict__ h0_cur, const float* __restrict__ h1_old,
    float* __restrict__ h1_new,
    const float* __restrict__ dh1, float* __restrict__ dh2)
{
  __shared__ float smem[4*32*33];
  const int blk = blockIdx.x;
  const int tid = threadIdx.x;
  const int tr = tid >> 5, tc = tid & 31;

  if (blk < 128) {
    // ---------------- fc2 ----------------------------------------------------
    const int bm = blk >> 3, bn = blk & 7;
    float acc[4][2] = {};
    float* Xs = smem;
    float* Ws = smem + 32*33;   // [64][33]
    for (int kt = 0; kt < 16; ++kt) {
      for (int l = tid; l < 32*32; l += 256) {
        int i = l >> 5, kk = l & 31;
        Xs[i*33+kk] = dh1[(size_t)(bm*32 + i)*HDIM + kt*32 + kk];
      }
      for (int l = tid; l < 64*32; l += 256) {
        int n = l >> 5, kk = l & 31;
        Ws[n*33+kk] = Wfc2[(size_t)(bn*64 + n)*HDIM + kt*32 + kk];
      }
      __syncthreads();
      #pragma unroll
      for (int kk = 0; kk < 32; ++kk) {
        float xv[4];
        #pragma unroll
        for (int q = 0; q < 4; ++q) xv[q] = Xs[(tr + 8*q)*33 + kk];
        float w0 = Ws[tc*33+kk], w1 = Ws[(tc+32)*33+kk];
        #pragma unroll
        for (int q = 0; q < 4; ++q) { acc[q][0] += xv[q]*w0; acc[q][1] += xv[q]*w1; }
      }
      __syncthreads();
    }
    #pragma unroll
    for (int q = 0; q < 4; ++q) {
      int b = bm*32 + tr + 8*q;
      int n0 = bn*64 + tc, n1 = n0 + 32;
      dh2[(size_t)b*HDIM + n0] = fmaxf(acc[q][0] + bfc2[n0], 0.f);
      dh2[(size_t)b*HDIM + n1] = fmaxf(acc[q][1] + bfc2[n1], 0.f);
    }
  } else {
    // ---------------- gru1 ---------------------------------------------------
    const int b2 = blk - 128;
    const int bm = b2 >> 4, bn = b2 & 15;
    float aR[4] = {}, aZ[4] = {}, aIN[4] = {}, aHN[4] = {};
    float* Xs = smem;
    float* Wr = smem + 1*32*33;
    float* Wz = smem + 2*32*33;
    float* Wn = smem + 3*32*33;
    // phase 1: gi = h0_cur @ Wih1^T, K=512
    for (int kt = 0; kt < 16; ++kt) {
      for (int l = tid; l < 32*32; l += 256) {
        int i = l >> 5, kk = l & 31;
        int k = kt*32 + kk;
        Xs[i*33+kk] = h0_cur[(size_t)(bm*32 + i)*RNND + k];
        int j = bn*32 + i;
        Wr[i*33+kk] = Wih1[(size_t)(j      )*RNND + k];
        Wz[i*33+kk] = Wih1[(size_t)(j + 512)*RNND + k];
        Wn[i*33+kk] = Wih1[(size_t)(j +1024)*RNND + k];
      }
      __syncthreads();
      #pragma unroll
      for (int kk = 0; kk < 32; ++kk) {
        float xv[4];
        #pragma unroll
        for (int q = 0; q < 4; ++q) xv[q] = Xs[(tr + 8*q)*33 + kk];
        float wr = Wr[tc*33+kk], wz = Wz[tc*33+kk], wn = Wn[tc*33+kk];
        #pragma unroll
        for (int q = 0; q < 4; ++q) { aR[q] += xv[q]*wr; aZ[q] += xv[q]*wz; aIN[q] += xv[q]*wn; }
      }
      __syncthreads();
    }
    // phase 2: gh = h1_old @ Whh1^T, K=512
    for (int kt = 0; kt < 16; ++kt) {
      for (int l = tid; l < 32*32; l += 256) {
        int i = l >> 5, kk = l & 31;
        int k = kt*32 + kk;
        Xs[i*33+kk] = h1_old[(size_t)(bm*32 + i)*RNND + k];
        int j = bn*32 + i;
        Wr[i*33+kk] = Whh1[(size_t)(j      )*RNND + k];
        Wz[i*33+kk] = Whh1[(size_t)(j + 512)*RNND + k];
        Wn[i*33+kk] = Whh1[(size_t)(j +1024)*RNND + k];
      }
      __syncthreads();
      #pragma unroll
      for (int kk = 0; kk < 32; ++kk) {
        float xv[4];
        #pragma unroll
        for (int q = 0; q < 4; ++q) xv[q] = Xs[(tr + 8*q)*33 + kk];
        float wr = Wr[tc*33+kk], wz = Wz[tc*33+kk], wn = Wn[tc*33+kk];
        #pragma unroll
        for (int q = 0; q < 4; ++q) { aR[q] += xv[q]*wr; aZ[q] += xv[q]*wz; aHN[q] += xv[q]*wn; }
      }
      __syncthreads();
    }
    const int j = bn*32 + tc;
    #pragma unroll
    for (int q = 0; q < 4; ++q) {
      int b = bm*32 + tr + 8*q;
      float r  = sigm(aR[q] + bih1[j]       + bhh1[j]);
      float zg = sigm(aZ[q] + bih1[j + 512] + bhh1[j + 512]);
      float n  = tanhf(aIN[q] + bih1[j +1024] + r*(aHN[q] + bhh1[j +1024]));
      float h  = h1_old[(size_t)b*RNND + j];
      h1_new[(size_t)b*RNND + j] = (1.f - zg)*n + zg*h;
    }
  }
}

extern "C" void kernel_launch(void* const* d_in, const int* in_sizes, int n_in,
                              void* d_out, int out_size, void* d_ws, size_t ws_size,
                              hipStream_t stream) {
  const float* states = (const float*)d_in[0];
  const float* zin    = (const float*)d_in[1];
  const float* Wih0   = (const float*)d_in[2];
  const float* Whh0   = (const float*)d_in[3];
  const float* bih0   = (const float*)d_in[4];
  const float* bhh0   = (const float*)d_in[5];
  const float* Wih1   = (const float*)d_in[6];
  const float* Whh1   = (const float*)d_in[7];
  const float* bih1   = (const float*)d_in[8];
  const float* bhh1   = (const float*)d_in[9];
  const float* Wfc1   = (const float*)d_in[10];
  const float* bfc1   = (const float*)d_in[11];
  const float* Wfc2   = (const float*)d_in[12];
  const float* bfc2   = (const float*)d_in[13];
  const float* Wmean  = (const float*)d_in[14];
  const float* bmean  = (const float*)d_in[15];
  const float* Wlv    = (const float*)d_in[16];
  const float* blv    = (const float*)d_in[17];
  float* out = (float*)d_out;
  float* ws  = (float*)d_ws;

  const size_t HBUF = (size_t)BATCH*RNND;   // 262144 floats
  float* h0a = ws;
  float* h0b = h0a + HBUF;
  float* h1a = h0b + HBUF;
  float* h1b = h1a + HBUF;
  float* dh1 = h1b + HBUF;
  float* dh2 = dh1 + HBUF;

  hipMemsetAsync(h0a, 0, HBUF*sizeof(float), stream);
  hipMemsetAsync(h1a, 0, HBUF*sizeof(float), stream);
  hipMemsetAsync(out, 0, (size_t)out_size*sizeof(float), stream);

  for (int t = 0; t <= NSTEP; ++t) {
    float* h0o = (t & 1) ? h0b : h0a;
    float* h0n = (t & 1) ? h0a : h0b;
    float* h1o = (t & 1) ? h1b : h1a;
    float* h1n = (t & 1) ? h1a : h1b;
    kernelA<<<400, 256, 0, stream>>>(t, states, zin, Wfc1, bfc1, Wih0, Whh0, bih0, bhh0,
                                     Wmean, bmean, Wlv, blv, h1o, h0o, h0n, dh1, dh2, out);
    if (t < NSTEP) {
      kernelB<<<384, 256, 0, stream>>>(Wfc2, bfc2, Wih1, Whh1, bih1, bhh1,
                                       h0n, h1o, h1n, dh1, dh2);
    }
  }
}

// Round 2
// 10010.360 us; speedup vs baseline: 4.1333x; 4.1333x over previous
//
#include <hip/hip_runtime.h>
#include <math.h>

#define BATCH 512
#define NSTEP 254
#define LOG2PI 1.8378770664093453f

typedef __attribute__((ext_vector_type(8))) short bfrag;   // 8 bf16 = 4 VGPR (MFMA A/B)
typedef __attribute__((ext_vector_type(4))) float f32x4;   // MFMA C/D

__device__ __forceinline__ float sigm(float x){ return 1.0f/(1.0f+__expf(-x)); }

__device__ __forceinline__ unsigned short f2bf(float f){
  unsigned int u = __builtin_bit_cast(unsigned int, f);
  u += 0x7FFFu + ((u>>16)&1u);          // RNE
  return (unsigned short)(u>>16);
}
__device__ __forceinline__ bfrag cvt8(const float* __restrict__ p){
  bfrag v;
  #pragma unroll
  for (int e=0;e<8;++e) v[e] = (short)f2bf(p[e]);
  return v;
}
__device__ __forceinline__ bfrag cvt8d(const float* __restrict__ p1, const float* __restrict__ p0){
  bfrag v;
  #pragma unroll
  for (int e=0;e<8;++e) v[e] = (short)f2bf(p1[e]-p0[e]);
  return v;
}

// f32 -> bf16 weight/z conversion pre-pass. blockIdx.y selects segment.
__global__ __launch_bounds__(256) void convertK(
  const float* __restrict__ Wfc1, const float* __restrict__ Wfc2,
  const float* __restrict__ Wih0, const float* __restrict__ Whh0,
  const float* __restrict__ Wih1, const float* __restrict__ Whh1,
  const float* __restrict__ Wmean, const float* __restrict__ Wlv,
  const float* __restrict__ zin,
  unsigned short* __restrict__ wfc1bf, unsigned short* __restrict__ wfc2bf,
  unsigned short* __restrict__ wih0bf, unsigned short* __restrict__ whh0bf,
  unsigned short* __restrict__ wih1bf, unsigned short* __restrict__ whh1bf,
  unsigned short* __restrict__ wheadbf, unsigned short* __restrict__ zbf)
{
  const float* src = nullptr; unsigned short* dst = nullptr; int n = 0;
  switch (blockIdx.y) {
    case 0: src=Wfc1;  dst=wfc1bf;        n=311296; break;
    case 1: src=Wfc2;  dst=wfc2bf;        n=262144; break;
    case 2: src=Wih0;  dst=wih0bf;        n=98304;  break;
    case 3: src=Whh0;  dst=whh0bf;        n=786432; break;
    case 4: src=Wih1;  dst=wih1bf;        n=786432; break;
    case 5: src=Whh1;  dst=whh1bf;        n=786432; break;
    case 6: src=Wmean; dst=wheadbf;       n=16384;  break;
    case 7: src=Wlv;   dst=wheadbf+16384; n=16384;  break;
    case 8: src=zin;   dst=zbf;           n=32768;  break;
  }
  for (int i = blockIdx.x*256 + threadIdx.x; i < n; i += gridDim.x*256)
    dst[i] = f2bf(src[i]);
}

// ---------------------------------------------------------------------------
// kernel A: blocks [0,64):    fc1   dh1 = relu([s,z,h1]@Wfc1^T+b)   64x64 tiles
//           blocks [64,192):  gru0  h0_new = GRU([s,a], h0_old)     64x32 tiles
//           blocks [192,200): head(t-1): mean/lv from dh2 -> nll    64x64 tiles
// ---------------------------------------------------------------------------
__global__ __launch_bounds__(256) void kernelA(
  int ts,
  const float* __restrict__ states,
  const unsigned short* __restrict__ zbf,
  const unsigned short* __restrict__ Wfc1bf, const float* __restrict__ bfc1,
  const unsigned short* __restrict__ Wih0bf, const unsigned short* __restrict__ Whh0bf,
  const float* __restrict__ bih0, const float* __restrict__ bhh0,
  const unsigned short* __restrict__ Wheadbf,
  const float* __restrict__ bmean, const float* __restrict__ blv,
  const unsigned short* __restrict__ h1bf_old,
  const unsigned short* __restrict__ h0bf_old, const float* __restrict__ h0f_old,
  unsigned short* __restrict__ h0bf_new, float* __restrict__ h0f_new,
  unsigned short* __restrict__ dh1bf, const unsigned short* __restrict__ dh2bf,
  float* __restrict__ nll)
{
  __shared__ unsigned short sm[12800];   // 25.6 KB
  const int tid  = threadIdx.x;
  const int lane = tid & 63;
  const int wv   = tid >> 6;
  const int r16  = lane & 15, kg = lane >> 4;
  const int blk  = blockIdx.x;

  if (blk < 64) {                         // ---------------- fc1 ----------------
    if (ts >= NSTEP) return;
    const int bm = blk >> 3, bn = blk & 7;
    const int wrow = (wv>>1)*32, wcol = (wv&1)*32;
    f32x4 acc[2][2] = {};
    const int row = tid>>2, ch = tid&3;
    const int b = bm*64 + row, n = bn*64 + row;
    const float* sbase = states + ((size_t)ts*BATCH + b)*32;
    for (int kt = 0; kt < 19; ++kt) {
      int k = kt*32 + ch*8;
      bfrag xv;
      if (k < 32)       xv = cvt8(sbase + k);
      else if (k < 96)  xv = *(const bfrag*)&zbf[b*64 + (k-32)];
      else              xv = *(const bfrag*)&h1bf_old[(size_t)b*512 + (k-96)];
      *(bfrag*)&sm[row*40 + ch*8] = xv;
      *(bfrag*)&sm[2560 + row*40 + ch*8] = *(const bfrag*)&Wfc1bf[(size_t)n*608 + k];
      __syncthreads();
      bfrag af[2], bfr[2];
      #pragma unroll
      for (int fm=0; fm<2; ++fm) af[fm]  = *(const bfrag*)&sm[(wrow+fm*16+r16)*40 + kg*8];
      #pragma unroll
      for (int fn=0; fn<2; ++fn) bfr[fn] = *(const bfrag*)&sm[2560 + (wcol+fn*16+r16)*40 + kg*8];
      #pragma unroll
      for (int fm=0; fm<2; ++fm)
        #pragma unroll
        for (int fn=0; fn<2; ++fn)
          acc[fm][fn] = __builtin_amdgcn_mfma_f32_16x16x32_bf16(af[fm], bfr[fn], acc[fm][fn], 0,0,0);
      __syncthreads();
    }
    #pragma unroll
    for (int fm=0; fm<2; ++fm)
      #pragma unroll
      for (int fn=0; fn<2; ++fn) {
        int nn = bn*64 + wcol + fn*16 + r16;
        float bias = bfc1[nn];
        #pragma unroll
        for (int e=0; e<4; ++e) {
          int bb = bm*64 + wrow + fm*16 + kg*4 + e;
          dh1bf[(size_t)bb*512 + nn] = f2bf(fmaxf(acc[fm][fn][e] + bias, 0.f));
        }
      }
  } else if (blk < 192) {                 // ---------------- gru0 ----------------
    if (ts >= NSTEP) return;
    const int g  = blk - 64;
    const int bm = g >> 4, jt = g & 15;   // batch tile(64), j tile(32)
    const int wrow = (wv>>1)*32, wcol = (wv&1)*16;
    f32x4 R[2]={}, Z[2]={}, NI[2]={}, NH[2]={};
    const float* s0 = states + (size_t)ts*BATCH*32;
    const float* s1 = s0 + BATCH*32;
    const int row = tid>>2, ch = tid&3;
    // prologue: gi = [s,a] @ Wih0^T, K=64
    #pragma unroll
    for (int kt = 0; kt < 2; ++kt) {
      int k0 = kt*32;
      { int k = k0 + ch*8, b = bm*64 + row;
        bfrag xv;
        if (k < 32) xv = cvt8(&s0[(size_t)b*32 + k]);
        else        xv = cvt8d(&s1[(size_t)b*32 + (k-32)], &s0[(size_t)b*32 + (k-32)]);
        *(bfrag*)&sm[row*40 + ch*8] = xv; }
      for (int sidx = tid; sidx < 384; sidx += 256) {
        int m = sidx>>7, slot = sidx&127, rr = slot>>2, c2 = slot&3;
        int j = jt*32 + rr;
        *(bfrag*)&sm[2560 + m*1280 + rr*40 + c2*8] =
            *(const bfrag*)&Wih0bf[((size_t)(m*512) + j)*64 + k0 + c2*8];
      }
      __syncthreads();
      bfrag a0[2];
      #pragma unroll
      for (int fm=0; fm<2; ++fm) a0[fm] = *(const bfrag*)&sm[(wrow+fm*16+r16)*40 + kg*8];
      bfrag br = *(const bfrag*)&sm[2560      + (wcol+r16)*40 + kg*8];
      bfrag bz = *(const bfrag*)&sm[2560+1280 + (wcol+r16)*40 + kg*8];
      bfrag bn = *(const bfrag*)&sm[2560+2560 + (wcol+r16)*40 + kg*8];
      #pragma unroll
      for (int fm=0; fm<2; ++fm) {
        R [fm] = __builtin_amdgcn_mfma_f32_16x16x32_bf16(a0[fm], br, R [fm], 0,0,0);
        Z [fm] = __builtin_amdgcn_mfma_f32_16x16x32_bf16(a0[fm], bz, Z [fm], 0,0,0);
        NI[fm] = __builtin_amdgcn_mfma_f32_16x16x32_bf16(a0[fm], bn, NI[fm], 0,0,0);
      }
      __syncthreads();
    }
    // main: gh = h0_old @ Whh0^T, K=512
    for (int kt = 0; kt < 16; ++kt) {
      int k0 = kt*32;
      { int b = bm*64 + row;
        *(bfrag*)&sm[row*40 + ch*8] = *(const bfrag*)&h0bf_old[(size_t)b*512 + k0 + ch*8]; }
      for (int sidx = tid; sidx < 384; sidx += 256) {
        int m = sidx>>7, slot = sidx&127, rr = slot>>2, c2 = slot&3;
        int j = jt*32 + rr;
        *(bfrag*)&sm[2560 + m*1280 + rr*40 + c2*8] =
            *(const bfrag*)&Whh0bf[((size_t)(m*512) + j)*512 + k0 + c2*8];
      }
      __syncthreads();
      bfrag a0[2];
      #pragma unroll
      for (int fm=0; fm<2; ++fm) a0[fm] = *(const bfrag*)&sm[(wrow+fm*16+r16)*40 + kg*8];
      bfrag br = *(const bfrag*)&sm[2560      + (wcol+r16)*40 + kg*8];
      bfrag bz = *(const bfrag*)&sm[2560+1280 + (wcol+r16)*40 + kg*8];
      bfrag bn = *(const bfrag*)&sm[2560+2560 + (wcol+r16)*40 + kg*8];
      #pragma unroll
      for (int fm=0; fm<2; ++fm) {
        R [fm] = __builtin_amdgcn_mfma_f32_16x16x32_bf16(a0[fm], br, R [fm], 0,0,0);
        Z [fm] = __builtin_amdgcn_mfma_f32_16x16x32_bf16(a0[fm], bz, Z [fm], 0,0,0);
        NH[fm] = __builtin_amdgcn_mfma_f32_16x16x32_bf16(a0[fm], bn, NH[fm], 0,0,0);
      }
      __syncthreads();
    }
    const int j = jt*32 + wcol + r16;
    const float brb = bih0[j]      + bhh0[j];
    const float bzb = bih0[j+512]  + bhh0[j+512];
    const float bin = bih0[j+1024], bhn = bhh0[j+1024];
    #pragma unroll
    for (int fm=0; fm<2; ++fm)
      #pragma unroll
      for (int e=0; e<4; ++e) {
        int bb = bm*64 + wrow + fm*16 + kg*4 + e;
        float r  = sigm(R[fm][e] + brb);
        float zg = sigm(Z[fm][e] + bzb);
        float nn = tanhf(NI[fm][e] + bin + r*(NH[fm][e] + bhn));
        float hold = h0f_old[(size_t)bb*512 + j];
        float hn = (1.f - zg)*nn + zg*hold;
        h0f_new [(size_t)bb*512 + j] = hn;
        h0bf_new[(size_t)bb*512 + j] = f2bf(hn);
      }
  } else {                                // ---------------- head(t-1) ----------------
    if (ts < 1) return;
    const int tp = ts - 1;
    const int hb = blk - 192;
    const int wrow = (wv>>1)*32, wcol = (wv&1)*32;
    f32x4 acc[2][2] = {};
    const int row = tid>>2, ch = tid&3;
    for (int kt = 0; kt < 16; ++kt) {
      int k = kt*32 + ch*8;
      *(bfrag*)&sm[row*40 + ch*8]        = *(const bfrag*)&dh2bf[(size_t)(hb*64 + row)*512 + k];
      *(bfrag*)&sm[2560 + row*40 + ch*8] = *(const bfrag*)&Wheadbf[(size_t)row*512 + k];
      __syncthreads();
      bfrag af[2], bfr[2];
      #pragma unroll
      for (int fm=0; fm<2; ++fm) af[fm]  = *(const bfrag*)&sm[(wrow+fm*16+r16)*40 + kg*8];
      #pragma unroll
      for (int fn=0; fn<2; ++fn) bfr[fn] = *(const bfrag*)&sm[2560 + (wcol+fn*16+r16)*40 + kg*8];
      #pragma unroll
      for (int fm=0; fm<2; ++fm)
        #pragma unroll
        for (int fn=0; fn<2; ++fn)
          acc[fm][fn] = __builtin_amdgcn_mfma_f32_16x16x32_bf16(af[fm], bfr[fn], acc[fm][fn], 0,0,0);
      __syncthreads();
    }
    float* mlv = (float*)sm;              // [64][66]
    #pragma unroll
    for (int fm=0; fm<2; ++fm)
      #pragma unroll
      for (int fn=0; fn<2; ++fn) {
        int col = wcol + fn*16 + r16;
        float bias = (col < 32) ? bmean[col] : blv[col-32];
        #pragma unroll
        for (int e=0; e<4; ++e) {
          int rl = wrow + fm*16 + kg*4 + e;
          mlv[rl*66 + col] = acc[fm][fn][e] + bias;
        }
      }
    __syncthreads();
    for (int idx = tid; idx < 2048; idx += 256) {
      int bl = idx>>5, i = idx&31;
      float mean = mlv[bl*66 + i], lv = mlv[bl*66 + 32 + i];
      int b = hb*64 + bl;
      const float* p0 = states + ((size_t)tp*BATCH + b)*32;
      float a = p0[BATCH*32 + i] - p0[i];
      float d = a - mean;
      nll[b*32 + i] += 0.5f*(d*d*__expf(-lv) + lv + LOG2PI);
    }
  }
}

// ---------------------------------------------------------------------------
// kernel B: blocks [0,64):   fc2  dh2 = relu(dh1@Wfc2^T+b)        64x64 tiles
//           blocks [64,192): gru1 h1_new = GRU(h0_cur, h1_old)    64x32 tiles
// ---------------------------------------------------------------------------
__global__ __launch_bounds__(256) void kernelB(
  const unsigned short* __restrict__ Wfc2bf, const float* __restrict__ bfc2,
  const unsigned short* __restrict__ Wih1bf, const unsigned short* __restrict__ Whh1bf,
  const float* __restrict__ bih1, const float* __restrict__ bhh1,
  const unsigned short* __restrict__ h0bf_cur,
  const unsigned short* __restrict__ h1bf_old, const float* __restrict__ h1f_old,
  unsigned short* __restrict__ h1bf_new, float* __restrict__ h1f_new,
  const unsigned short* __restrict__ dh1bf, unsigned short* __restrict__ dh2bf)
{
  __shared__ unsigned short sm[12800];
  const int tid  = threadIdx.x;
  const int lane = tid & 63;
  const int wv   = tid >> 6;
  const int r16  = lane & 15, kg = lane >> 4;
  const int blk  = blockIdx.x;

  if (blk < 64) {                         // ---------------- fc2 ----------------
    const int bm = blk >> 3, bn = blk & 7;
    const int wrow = (wv>>1)*32, wcol = (wv&1)*32;
    f32x4 acc[2][2] = {};
    const int row = tid>>2, ch = tid&3;
    for (int kt = 0; kt < 16; ++kt) {
      int k = kt*32 + ch*8;
      *(bfrag*)&sm[row*40 + ch*8]        = *(const bfrag*)&dh1bf[(size_t)(bm*64 + row)*512 + k];
      *(bfrag*)&sm[2560 + row*40 + ch*8] = *(const bfrag*)&Wfc2bf[(size_t)(bn*64 + row)*512 + k];
      __syncthreads();
      bfrag af[2], bfr[2];
      #pragma unroll
      for (int fm=0; fm<2; ++fm) af[fm]  = *(const bfrag*)&sm[(wrow+fm*16+r16)*40 + kg*8];
      #pragma unroll
      for (int fn=0; fn<2; ++fn) bfr[fn] = *(const bfrag*)&sm[2560 + (wcol+fn*16+r16)*40 + kg*8];
      #pragma unroll
      for (int fm=0; fm<2; ++fm)
        #pragma unroll
        for (int fn=0; fn<2; ++fn)
          acc[fm][fn] = __builtin_amdgcn_mfma_f32_16x16x32_bf16(af[fm], bfr[fn], acc[fm][fn], 0,0,0);
      __syncthreads();
    }
    #pragma unroll
    for (int fm=0; fm<2; ++fm)
      #pragma unroll
      for (int fn=0; fn<2; ++fn) {
        int nn = bn*64 + wcol + fn*16 + r16;
        float bias = bfc2[nn];
        #pragma unroll
        for (int e=0; e<4; ++e) {
          int bb = bm*64 + wrow + fm*16 + kg*4 + e;
          dh2bf[(size_t)bb*512 + nn] = f2bf(fmaxf(acc[fm][fn][e] + bias, 0.f));
        }
      }
  } else {                                // ---------------- gru1 ----------------
    const int g  = blk - 64;
    const int bm = g >> 4, jt = g & 15;
    const int wrow = (wv>>1)*32, wcol = (wv&1)*16;
    f32x4 R[2]={}, Z[2]={}, NI[2]={}, NH[2]={};
    const int row = tid>>2, ch = tid&3;
    for (int kt = 0; kt < 16; ++kt) {
      int k0 = kt*32;
      { int b = bm*64 + row, k = k0 + ch*8;
        *(bfrag*)&sm[row*40 + ch*8]        = *(const bfrag*)&h0bf_cur[(size_t)b*512 + k];
        *(bfrag*)&sm[2560 + row*40 + ch*8] = *(const bfrag*)&h1bf_old[(size_t)b*512 + k]; }
      for (int sidx = tid; sidx < 768; sidx += 256) {
        int m = sidx>>7, slot = sidx&127, rr = slot>>2, c2 = slot&3;
        int j = jt*32 + rr;
        const unsigned short* W = (m < 3) ? Wih1bf : Whh1bf;
        int mm = (m < 3) ? m : m - 3;
        *(bfrag*)&sm[5120 + m*1280 + rr*40 + c2*8] =
            *(const bfrag*)&W[((size_t)(mm*512) + j)*512 + k0 + c2*8];
      }
      __syncthreads();
      bfrag a0[2], a1[2];
      #pragma unroll
      for (int fm=0; fm<2; ++fm) {
        a0[fm] = *(const bfrag*)&sm[       (wrow+fm*16+r16)*40 + kg*8];
        a1[fm] = *(const bfrag*)&sm[2560 + (wrow+fm*16+r16)*40 + kg*8];
      }
      const int boff = (wcol + r16)*40 + kg*8;
      bfrag bir = *(const bfrag*)&sm[5120        + boff];
      bfrag biz = *(const bfrag*)&sm[5120+1280   + boff];
      bfrag bin = *(const bfrag*)&sm[5120+2560   + boff];
      bfrag bhr = *(const bfrag*)&sm[5120+3840   + boff];
      bfrag bhz = *(const bfrag*)&sm[5120+5120   + boff];
      bfrag bhn = *(const bfrag*)&sm[5120+6400   + boff];
      #pragma unroll
      for (int fm=0; fm<2; ++fm) {
        R [fm] = __builtin_amdgcn_mfma_f32_16x16x32_bf16(a0[fm], bir, R [fm], 0,0,0);
        R [fm] = __builtin_amdgcn_mfma_f32_16x16x32_bf16(a1[fm], bhr, R [fm], 0,0,0);
        Z [fm] = __builtin_amdgcn_mfma_f32_16x16x32_bf16(a0[fm], biz, Z [fm], 0,0,0);
        Z [fm] = __builtin_amdgcn_mfma_f32_16x16x32_bf16(a1[fm], bhz, Z [fm], 0,0,0);
        NI[fm] = __builtin_amdgcn_mfma_f32_16x16x32_bf16(a0[fm], bin, NI[fm], 0,0,0);
        NH[fm] = __builtin_amdgcn_mfma_f32_16x16x32_bf16(a1[fm], bhn, NH[fm], 0,0,0);
      }
      __syncthreads();
    }
    const int j = jt*32 + wcol + r16;
    const float brb = bih1[j]      + bhh1[j];
    const float bzb = bih1[j+512]  + bhh1[j+512];
    const float bin = bih1[j+1024], bhn = bhh1[j+1024];
    #pragma unroll
    for (int fm=0; fm<2; ++fm)
      #pragma unroll
      for (int e=0; e<4; ++e) {
        int bb = bm*64 + wrow + fm*16 + kg*4 + e;
        float r  = sigm(R[fm][e] + brb);
        float zg = sigm(Z[fm][e] + bzb);
        float nn = tanhf(NI[fm][e] + bin + r*(NH[fm][e] + bhn));
        float hold = h1f_old[(size_t)bb*512 + j];
        float hn = (1.f - zg)*nn + zg*hold;
        h1f_new [(size_t)bb*512 + j] = hn;
        h1bf_new[(size_t)bb*512 + j] = f2bf(hn);
      }
  }
}

extern "C" void kernel_launch(void* const* d_in, const int* in_sizes, int n_in,
                              void* d_out, int out_size, void* d_ws, size_t ws_size,
                              hipStream_t stream) {
  const float* states = (const float*)d_in[0];
  const float* zin    = (const float*)d_in[1];
  const float* Wih0   = (const float*)d_in[2];
  const float* Whh0   = (const float*)d_in[3];
  const float* bih0   = (const float*)d_in[4];
  const float* bhh0   = (const float*)d_in[5];
  const float* Wih1   = (const float*)d_in[6];
  const float* Whh1   = (const float*)d_in[7];
  const float* bih1   = (const float*)d_in[8];
  const float* bhh1   = (const float*)d_in[9];
  const float* Wfc1   = (const float*)d_in[10];
  const float* bfc1   = (const float*)d_in[11];
  const float* Wfc2   = (const float*)d_in[12];
  const float* bfc2   = (const float*)d_in[13];
  const float* Wmean  = (const float*)d_in[14];
  const float* bmean  = (const float*)d_in[15];
  const float* Wlv    = (const float*)d_in[16];
  const float* blv    = (const float*)d_in[17];
  float* out = (float*)d_out;

  const size_t HB = (size_t)512*512;           // 262144
  float* f = (float*)d_ws;
  float* h0f[2] = { f,        f + HB   };
  float* h1f[2] = { f + 2*HB, f + 3*HB };
  unsigned short* u = (unsigned short*)(f + 4*HB);
  unsigned short* h0bf[2] = { u,        u + HB   };
  unsigned short* h1bf[2] = { u + 2*HB, u + 3*HB };
  unsigned short* dh1bf = u + 4*HB;
  unsigned short* dh2bf = u + 5*HB;
  unsigned short* wp = u + 6*HB;
  unsigned short* wfc1bf = wp;  wp += 311296;
  unsigned short* wfc2bf = wp;  wp += 262144;
  unsigned short* wih0bf = wp;  wp += 98304;
  unsigned short* whh0bf = wp;  wp += 786432;
  unsigned short* wih1bf = wp;  wp += 786432;
  unsigned short* whh1bf = wp;  wp += 786432;
  unsigned short* wheadbf= wp;  wp += 32768;
  unsigned short* zbf    = wp;  wp += 32768;

  hipMemsetAsync(f, 0, 4*HB*sizeof(float), stream);                 // h0f/h1f
  hipMemsetAsync(u, 0, 4*HB*sizeof(unsigned short), stream);        // h0bf/h1bf
  hipMemsetAsync(out, 0, (size_t)out_size*sizeof(float), stream);

  convertK<<<dim3(96,9), 256, 0, stream>>>(Wfc1, Wfc2, Wih0, Whh0, Wih1, Whh1,
                                           Wmean, Wlv, zin,
                                           wfc1bf, wfc2bf, wih0bf, whh0bf,
                                           wih1bf, whh1bf, wheadbf, zbf);

  for (int ts = 0; ts <= NSTEP; ++ts) {
    int od = ts & 1, nw = od ^ 1;
    kernelA<<<200, 256, 0, stream>>>(ts, states, zbf, wfc1bf, bfc1,
                                     wih0bf, whh0bf, bih0, bhh0,
                                     wheadbf, bmean, blv,
                                     h1bf[od], h0bf[od], h0f[od],
                                     h0bf[nw], h0f[nw], dh1bf, dh2bf, out);
    if (ts < NSTEP) {
      kernelB<<<192, 256, 0, stream>>>(wfc2bf, bfc2, wih1bf, whh1bf, bih1, bhh1,
                                       h0bf[nw], h1bf[od], h1f[od],
                                       h1bf[nw], h1f[nw], dh1bf, dh2bf);
    }
  }
}